// Round 20
// baseline (388.167 us; speedup 1.0000x reference)
//
#include <hip/hip_runtime.h>
#include <hip/hip_bf16.h>

typedef __attribute__((ext_vector_type(4))) float f32x4;
typedef __attribute__((ext_vector_type(16))) float f32x16;
typedef __attribute__((ext_vector_type(4))) float fl4;
typedef __attribute__((ext_vector_type(8))) short s16x8;
typedef __attribute__((ext_vector_type(4))) short s16x4;

#define SCALING_C 0.1889822365046136f
// p = exp(50*tanh(y/50)) = exp2(y*(L + y2*(P1*L + y2*P2*L))), L=log2(e)
#define L2E 1.4426950408889634f
#define PC1 (-1.9235933e-4f)   // -1/7500 * L2E
#define PC2 (3.0777493e-8f)    //  2/93750000 * L2E
#define QKV_STRIDE 6144

__device__ __forceinline__ short f2bf(float f) {
  union { float f; unsigned u; } v; v.f = f;
  unsigned r = v.u + 0x7fffu + ((v.u >> 16) & 1u);
  return (short)(r >> 16);
}
__device__ __forceinline__ float bf2f(short s) {
  union { unsigned u; float f; } v; v.u = ((unsigned)(unsigned short)s) << 16;
  return v.f;
}
__device__ __forceinline__ unsigned cvtpk(float a, float b) {
  unsigned r;
  asm("v_cvt_pk_bf16_f32 %0, %1, %2" : "=v"(r) : "v"(a), "v"(b));
  return r;   // D[15:0]=bf16(a), D[31:16]=bf16(b)
}

#define GLOAD_LDS16(g, l)                                                          \
  __builtin_amdgcn_global_load_lds(                                                \
      (const __attribute__((address_space(1))) void*)(g),                          \
      (__attribute__((address_space(3))) void*)(l), 16, 0, 0)

// ---------------- transpose + fp32->bf16 convert: WT[n][k] = bf16(W[k][n]) -----
__global__ __launch_bounds__(256)
void convT_kernel(const float* __restrict__ W, short* __restrict__ WT, int K, int N) {
  __shared__ float T[64][65];
  const int tx = threadIdx.x, ty = threadIdx.y;   // (64,4)
  const int k0 = blockIdx.x * 64, n0 = blockIdx.y * 64;
#pragma unroll
  for (int i = 0; i < 16; ++i) {
    int r = ty + i * 4;
    T[r][tx] = W[(size_t)(k0 + r) * N + n0 + tx];
  }
  __syncthreads();
#pragma unroll
  for (int i = 0; i < 16; ++i) {
    int r = ty + i * 4;
    WT[(size_t)(n0 + r) * K + k0 + tx] = f2bf(T[tx][r]);
  }
}

// ---------------- bf16 transpose of the V slice: Vtg[g][d][kv] -----------------
__global__ __launch_bounds__(256)
void transV_kernel(const short* __restrict__ Vsrc, short* __restrict__ Vtg) {
  __shared__ short T[64][72];
  const int tx = threadIdx.x, ty = threadIdx.y;   // (64,4)
  const int kv0 = blockIdx.x * 64, d0 = blockIdx.y * 64, g = blockIdx.z;
  const short* src = Vsrc + (size_t)kv0 * QKV_STRIDE + g * 128 + d0;
#pragma unroll
  for (int i = 0; i < 16; ++i) {
    int r = ty + i * 4;
    T[r][tx] = src[(size_t)r * QKV_STRIDE + tx];
  }
  __syncthreads();
  short* dst = Vtg + (size_t)g * 128 * 2048 + (size_t)d0 * 2048 + kv0;
#pragma unroll
  for (int i = 0; i < 16; ++i) {
    int r = ty + i * 4;
    dst[(size_t)r * 2048 + tx] = T[tx][r];
  }
}

// ---------------- fp32 -> bf16 elementwise (hidden states) ----------------
__global__ __launch_bounds__(256)
void conv16_kernel(const float* __restrict__ X, short* __restrict__ Y, int n4) {
  int i = blockIdx.x * 256 + threadIdx.x;
  if (i < n4) {
    fl4 v = *(const fl4*)&X[(size_t)i * 4];
    s16x4 o;
    o[0] = f2bf(v[0]); o[1] = f2bf(v[1]); o[2] = f2bf(v[2]); o[3] = f2bf(v[3]);
    *(s16x4*)&Y[(size_t)i * 4] = o;
  }
}

// ---------------- GEMM v4: 3-buffer 2-deep pipeline, counted vmcnt (T4) --------
// Loads for tile t+2 issue in iter t, awaited end of iter t+1 => a FULL iteration
// of latency cover (r18's 1-deep window was shorter than load latency). Steady
// state waits vmcnt(8) (older stage of 16 outstanding), never a full drain.
// LDS 96KB -> 1 block/CU; the pipeline, not TLP, hides latency. BK=64 swizzle
// (8 chunks/row) retained: r19 showed BK=32's 4-chunk rows alias 4-way.
template<int OUT_BF16>
__global__ __launch_bounds__(256, 1)
void gemm_bb(const short* __restrict__ A, const short* __restrict__ Bt,
             void* __restrict__ Cv, int N, int K) {
  __shared__ short As[3][8192];   // 128 rows x 64 shorts, chunk-XOR swizzled (r&7)
  __shared__ short Bs[3][8192];
  const int tid = threadIdx.x;
  const int bm = blockIdx.y, bn = blockIdx.x;
  const int wid = tid >> 6, lane = tid & 63;
  const int wr = (wid >> 1) * 64, wc = (wid & 1) * 64;
  const int ar = lane & 15, g = lane >> 4;

  const f32x4 fz = {0.f, 0.f, 0.f, 0.f};
  f32x4 acc[4][4];
#pragma unroll
  for (int m = 0; m < 4; ++m)
#pragma unroll
    for (int n = 0; n < 4; ++n) acc[m][n] = fz;

  const short* Abase = A + (size_t)(bm * 128) * K;
  const short* Bbase = Bt + (size_t)(bn * 128) * K;
  const int u0 = wid * 256 + lane;

  auto stage = [&](int b, int k0) {
#pragma unroll
    for (int i = 0; i < 4; ++i) {
      int u = u0 + i * 64;
      int r = u >> 3;
      int cs = (u & 7) ^ (r & 7);
      size_t goff = (size_t)r * K + k0 + cs * 8;
      GLOAD_LDS16(Abase + goff, &As[b][u * 8]);
      GLOAD_LDS16(Bbase + goff, &Bs[b][u * 8]);
    }
  };

  // prologue: stage tiles 0 and 1 (16 loads), wait for tile 0 (8 older), publish
  stage(0, 0);
  stage(1, 64);
  asm volatile("s_waitcnt vmcnt(8)" ::: "memory");
  __syncthreads();

  int b = 0;
  for (int k0 = 0; k0 < K; k0 += 64) {
    const bool pf = (k0 + 128 < K);
    if (pf) {
      int b2 = b + 2; if (b2 >= 3) b2 -= 3;
      stage(b2, k0 + 128);
    }

#pragma unroll
    for (int ks = 0; ks < 2; ++ks) {
      s16x8 af[4], bfr[4];
#pragma unroll
      for (int m = 0; m < 4; ++m) {
        int r = wr + m * 16 + ar;
        af[m] = *(const s16x8*)&As[b][r * 64 + (((ks * 4 + g) ^ (r & 7)) * 8)];
      }
#pragma unroll
      for (int n = 0; n < 4; ++n) {
        int r = wc + n * 16 + ar;
        bfr[n] = *(const s16x8*)&Bs[b][r * 64 + (((ks * 4 + g) ^ (r & 7)) * 8)];
      }
      __builtin_amdgcn_s_setprio(1);
#pragma unroll
      for (int m = 0; m < 4; ++m)
#pragma unroll
        for (int n = 0; n < 4; ++n)
          acc[m][n] = __builtin_amdgcn_mfma_f32_16x16x32_bf16(af[m], bfr[n], acc[m][n], 0, 0, 0);
      __builtin_amdgcn_s_setprio(0);
    }

    // counted wait: next tile's stage (issued LAST iter) must have landed;
    // this iter's stage (newest 8) may stay in flight across the barrier.
    if (pf) {
      asm volatile("s_waitcnt vmcnt(8)" ::: "memory");
    } else {
      asm volatile("s_waitcnt vmcnt(0)" ::: "memory");
    }
    __syncthreads();
    b = b + 1; if (b >= 3) b -= 3;
  }
  const int rr = (lane >> 4) * 4;
#pragma unroll
  for (int m = 0; m < 4; ++m)
#pragma unroll
    for (int n = 0; n < 4; ++n)
#pragma unroll
      for (int j = 0; j < 4; ++j) {
        int row = bm * 128 + wr + m * 16 + rr + j;
        int col = bn * 128 + wc + n * 16 + ar;
        if (OUT_BF16)
          ((short*)Cv)[(size_t)row * N + col] = f2bf(acc[m][n][j]);
        else
          ((float*)Cv)[(size_t)row * N + col] = acc[m][n][j];
      }
}

// ------- fused RMSNorm + RoPE on a column-slice of the fused QKV matrix --------
// scale folds the attention SCALING into Q (1.0 for K).
__global__ __launch_bounds__(256)
void normrope_kernel(short* __restrict__ X, const float* __restrict__ cosb,
                     const float* __restrict__ sinb, const float* __restrict__ w,
                     int hbits, int off, float scale) {
  const int wid = threadIdx.x >> 6, lane = threadIdx.x & 63;
  const int r = blockIdx.x * 4 + wid;
  const int s = r >> hbits, h = r & ((1 << hbits) - 1);
  const size_t base = (size_t)s * QKV_STRIDE + off + h * 128;
  float x1 = bf2f(X[base + lane]);
  float x2 = bf2f(X[base + 64 + lane]);
  float ss = x1 * x1 + x2 * x2;
#pragma unroll
  for (int m = 1; m < 64; m <<= 1) ss += __shfl_xor(ss, m);
  float inv = rsqrtf(ss * (1.0f / 128.0f) + 1e-6f) * scale;
  float n1 = x1 * inv * (1.0f + w[lane]);
  float n2 = x2 * inv * (1.0f + w[lane + 64]);
  float c1 = cosb[s * 128 + lane], sn1 = sinb[s * 128 + lane];
  float c2 = cosb[s * 128 + 64 + lane], sn2 = sinb[s * 128 + 64 + lane];
  X[base + lane] = f2bf(n1 * c1 - n2 * sn1);
  X[base + 64 + lane] = f2bf(n2 * c2 + n1 * sn2);
}

// ------------- flash attention v9: kv-parity split + HW cvt_pk/permlane --------
// (unchanged from round 14)
__global__ __launch_bounds__(512, 2)
void attn_kernel(const short* __restrict__ C, const short* __restrict__ Vtg,
                 short* __restrict__ O) {
  __shared__ short Ks[2][2][8192];   // [par][buf][kv 64][d 128], chunk-XOR (r&7)
  __shared__ short Vt[2][2][8192];   // [par][buf][d 128][kv 64], chunk-XOR (d&7)
  const int tid = threadIdx.x;
  const int par = tid >> 8;                   // kv parity
  const int t256 = tid & 255;
  const int bid = blockIdx.x;
  const int g = bid & 7;                      // kv-head, pinned to XCD g
  const int i0 = bid >> 3;
  const int h = g * 4 + (i0 & 3);
  const int c = 15 - (i0 >> 2);               // LPT: big chunks dispatch first
  const int wid4 = (tid >> 6) & 3;            // wave-in-parity: q sub-chunk
  const int lane = tid & 63;
  const int q32 = lane & 31, hi = lane >> 5;
  const int qw0 = c * 128 + wid4 * 32;        // wave's 32 q-rows
  const int NS = c + 1;                       // steps per parity (NT = 2c+2)

  const short* Kb = C + 4096 + g * 128;
  const short* Vb = Vtg + (size_t)g * 128 * 2048;

  s16x8 qf[8];
  f32x16 oacc[4];
  float l_part = 0.f;

  const short* Qrow = C + (size_t)(qw0 + q32) * QKV_STRIDE + h * 128 + hi * 8;
#pragma unroll
  for (int t = 0; t < 8; ++t) qf[t] = *(const s16x8*)(Qrow + t * 16);
#pragma unroll
  for (int db = 0; db < 4; ++db)
#pragma unroll
    for (int r = 0; r < 16; ++r) oacc[db][r] = 0.f;

  auto issueK = [&](int b, int kb) {
#pragma unroll
    for (int ii = 0; ii < 4; ++ii) {          // 4*256*16B = full 16KB tile
      int u = t256 + ii * 256;
      int r = u >> 4, cc = u & 15;
      GLOAD_LDS16(Kb + (size_t)(kb * 64 + r) * QKV_STRIDE + ((cc ^ (r & 7)) * 8),
                  &Ks[par][b][u * 8]);
    }
  };
  auto issueV = [&](int b, int kb) {
#pragma unroll
    for (int ii = 0; ii < 4; ++ii) {
      int u = t256 + ii * 256;
      int d = u >> 3, cc = u & 7;
      GLOAD_LDS16(Vb + (size_t)d * 2048 + kb * 64 + ((cc ^ (d & 7)) * 8),
                  &Vt[par][b][u * 8]);
    }
  };

  // prologue: parity's first tile is tile `par`
  issueK(0, par);
  issueV(0, par);
  asm volatile("s_waitcnt vmcnt(0)" ::: "memory");
  __syncthreads();

  int buf = 0;
  for (int step = 0; step < NS; ++step) {
    const int kb = 2 * step + par;
    if (step + 1 < NS) { issueK(buf ^ 1, kb + 2); issueV(buf ^ 1, kb + 2); }

    if (!(kb * 64 > qw0 + 31)) {               // wave not fully masked
      // ---- S^T = K Q^T (Q pre-scaled): sacc[m][r] = y[k=crow][q=q32] ----
      f32x16 sacc[2];
#pragma unroll
      for (int m = 0; m < 2; ++m)
#pragma unroll
        for (int r = 0; r < 16; ++r) sacc[m][r] = 0.f;
      __builtin_amdgcn_s_setprio(1);
#pragma unroll
      for (int t = 0; t < 8; ++t)
#pragma unroll
        for (int m = 0; m < 2; ++m) {
          int r = m * 32 + q32;
          s16x8 kf = *(const s16x8*)&Ks[par][buf][r * 128 + (((2 * t + hi) ^ (r & 7)) * 8)];
          sacc[m] = __builtin_amdgcn_mfma_f32_32x32x16_bf16(kf, qf[t], sacc[m], 0, 0, 0);
        }
      __builtin_amdgcn_s_setprio(0);

      // ---- softcapped exp via exp2 (fixed max 0), causal mask ----
      const bool anymask = (kb * 64 + 63 > qw0);
#pragma unroll
      for (int m = 0; m < 2; ++m)
#pragma unroll
        for (int r = 0; r < 16; ++r) {
          float y = sacc[m][r];
          float y2 = y * y;
          float z = y * fmaf(y2, fmaf(y2, PC2, PC1), L2E);
          float p = exp2f(z);
          if (anymask) {
            int kk = kb * 64 + m * 32 + (r & 3) + 8 * (r >> 2) + 4 * hi;
            if (kk > qw0 + q32) p = 0.f;
          }
          l_part += p;
          sacc[m][r] = p;
        }

      // ---- P -> A-frags: cvt_pk + permlane32_swap ; O += P V ----
#pragma unroll
      for (int ks = 0; ks < 4; ++ks) {
        const int m = ks >> 1, r0 = (ks & 1) * 8;
        unsigned a0 = cvtpk(sacc[m][r0 + 0], sacc[m][r0 + 1]);
        unsigned a1 = cvtpk(sacc[m][r0 + 2], sacc[m][r0 + 3]);
        unsigned b0 = cvtpk(sacc[m][r0 + 4], sacc[m][r0 + 5]);
        unsigned b1 = cvtpk(sacc[m][r0 + 6], sacc[m][r0 + 7]);
        // swap: a' = lane<32 ? a : b[lane-32]; b' = lane<32 ? a[lane+32] : b
        asm("v_permlane32_swap_b32 %0, %1" : "+v"(a0), "+v"(b0));
        asm("v_permlane32_swap_b32 %0, %1" : "+v"(a1), "+v"(b1));
        union { s16x8 v; unsigned w[4]; } pw;
        pw.w[0] = a0; pw.w[1] = a1; pw.w[2] = b0; pw.w[3] = b1;
        __builtin_amdgcn_s_setprio(1);
#pragma unroll
        for (int db = 0; db < 4; ++db) {
          int d = db * 32 + q32;
          s16x8 vf = *(const s16x8*)&Vt[par][buf][d * 64 + (((2 * ks + hi) ^ (d & 7)) * 8)];
          oacc[db] = __builtin_amdgcn_mfma_f32_32x32x16_bf16(pw.v, vf, oacc[db], 0, 0, 0);
        }
        __builtin_amdgcn_s_setprio(0);
      }
    }

    // single sync point per step
    asm volatile("s_waitcnt vmcnt(0)" ::: "memory");
    __syncthreads();
    buf ^= 1;
  }

  // ---- combine parity partials (fixed-max => exactly additive) ----
  float* sk = (float*)&Ks[0][0][0];            // 64KB: 256 lanes x 64 f32
  float* lv = (float*)&Vt[0][0][0];            // 1KB: 256 lanes
  const int lid = wid4 * 64 + lane;
  if (par == 1) {
#pragma unroll
    for (int db = 0; db < 4; ++db)
#pragma unroll
      for (int r = 0; r < 16; ++r) sk[lid + (db * 16 + r) * 256] = oacc[db][r];
    lv[lid] = l_part;
  }
  __syncthreads();
  if (par == 0) {
#pragma unroll
    for (int db = 0; db < 4; ++db)
#pragma unroll
      for (int r = 0; r < 16; ++r) oacc[db][r] += sk[lid + (db * 16 + r) * 256];
    l_part += lv[lid];

    // ---- epilogue: l gather, divide, store ----
    float lt = l_part + __shfl_xor(l_part, 32);
    float rl[16];
#pragma unroll
    for (int r = 0; r < 16; ++r)
      rl[r] = 1.0f / __shfl(lt, (r & 3) + 8 * (r >> 2) + 4 * hi);
#pragma unroll
    for (int db = 0; db < 4; ++db)
#pragma unroll
      for (int r = 0; r < 16; ++r) {
        int q = qw0 + (r & 3) + 8 * (r >> 2) + 4 * hi;
        int d = db * 32 + q32;
        O[(size_t)q * 4096 + h * 128 + d] = f2bf(oacc[db][r] * rl[r]);
      }
  }
}

extern "C" void kernel_launch(void* const* d_in, const int* in_sizes, int n_in,
                              void* d_out, int out_size, void* d_ws, size_t ws_size,
                              hipStream_t stream) {
  const float* hs   = (const float*)d_in[0];
  const float* cosb = (const float*)d_in[1];
  const float* sinb = (const float*)d_in[2];
  // d_in[3]: causal mask, applied analytically
  const float* Wq = (const float*)d_in[4];
  const float* Wk = (const float*)d_in[5];
  const float* Wv = (const float*)d_in[6];
  const float* Wo = (const float*)d_in[7];
  const float* qw = (const float*)d_in[8];
  const float* kw = (const float*)d_in[9];
  float* out = (float*)d_out;

  char* ws = (char*)d_ws;
  short* hsb = (short*)ws;                        // [0, 10.49M)  2048x2560
  short* WT  = (short*)(ws + 10485760);           // [10.49, 41.94M) 6144x2560 fused
  short* WkT = WT + (size_t)4096 * 2560;
  short* WvT = WT + (size_t)5120 * 2560;
  short* Cq  = (short*)(ws + 41943040);           // [41.94, 67.11M) 2048x6144 QKV
  short* ao  = (short*)ws;                        // [0, 16.78M) alias (dead after GEMMs)
  short* Vtg = (short*)(ws + 16777216);           // [16.78, 20.97M) 8x128x2048 (4MB gap)
  short* WoT = (short*)(ws + 20971520);           // [20.97, 41.94M) alias WT-tail

  dim3 blk(256), cblk(64, 4);
  convT_kernel<<<dim3(40, 64), cblk, 0, stream>>>(Wq, WT, 2560, 4096);
  convT_kernel<<<dim3(40, 16), cblk, 0, stream>>>(Wk, WkT, 2560, 1024);
  convT_kernel<<<dim3(40, 16), cblk, 0, stream>>>(Wv, WvT, 2560, 1024);
  conv16_kernel<<<5120, blk, 0, stream>>>(hs, hsb, 1310720);
  gemm_bb<1><<<dim3(48, 16), blk, 0, stream>>>(hsb, WT, Cq, 6144, 2560);
  normrope_kernel<<<16384, blk, 0, stream>>>(Cq, cosb, sinb, qw, 5, 0, SCALING_C);
  normrope_kernel<<<4096,  blk, 0, stream>>>(Cq, cosb, sinb, kw, 3, 4096, 1.0f);
  transV_kernel<<<dim3(32, 2, 8), cblk, 0, stream>>>(Cq + 5120, Vtg);
  convT_kernel<<<dim3(64, 40), cblk, 0, stream>>>(Wo, WoT, 4096, 2560);
  attn_kernel<<<dim3(512), dim3(512), 0, stream>>>(Cq, Vtg, ao);
  gemm_bb<0><<<dim3(20, 16), blk, 0, stream>>>(ao, WoT, out, 2560, 4096);
}

// Round 21
// 323.353 us; speedup vs baseline: 1.2004x; 1.2004x over previous
//
#include <hip/hip_runtime.h>
#include <hip/hip_bf16.h>

typedef __attribute__((ext_vector_type(4))) float f32x4;
typedef __attribute__((ext_vector_type(16))) float f32x16;
typedef __attribute__((ext_vector_type(4))) float fl4;
typedef __attribute__((ext_vector_type(8))) short s16x8;
typedef __attribute__((ext_vector_type(4))) short s16x4;

#define SCALING_C 0.1889822365046136f
// p = exp(50*tanh(y/50)) = exp2(y*(L + y2*(P1*L + y2*P2*L))), L=log2(e)
#define L2E 1.4426950408889634f
#define PC1 (-1.9235933e-4f)   // -1/7500 * L2E
#define PC2 (3.0777493e-8f)    //  2/93750000 * L2E
#define QKV_STRIDE 6144

__device__ __forceinline__ short f2bf(float f) {
  union { float f; unsigned u; } v; v.f = f;
  unsigned r = v.u + 0x7fffu + ((v.u >> 16) & 1u);
  return (short)(r >> 16);
}
__device__ __forceinline__ float bf2f(short s) {
  union { unsigned u; float f; } v; v.u = ((unsigned)(unsigned short)s) << 16;
  return v.f;
}
__device__ __forceinline__ unsigned cvtpk(float a, float b) {
  unsigned r;
  asm("v_cvt_pk_bf16_f32 %0, %1, %2" : "=v"(r) : "v"(a), "v"(b));
  return r;   // D[15:0]=bf16(a), D[31:16]=bf16(b)
}

#define GLOAD_LDS16(g, l)                                                          \
  __builtin_amdgcn_global_load_lds(                                                \
      (const __attribute__((address_space(1))) void*)(g),                          \
      (__attribute__((address_space(3))) void*)(l), 16, 0, 0)

// ---------------- transpose + fp32->bf16 convert: WT[n][k] = bf16(W[k][n]) -----
__global__ __launch_bounds__(256)
void convT_kernel(const float* __restrict__ W, short* __restrict__ WT, int K, int N) {
  __shared__ float T[64][65];
  const int tx = threadIdx.x, ty = threadIdx.y;   // (64,4)
  const int k0 = blockIdx.x * 64, n0 = blockIdx.y * 64;
#pragma unroll
  for (int i = 0; i < 16; ++i) {
    int r = ty + i * 4;
    T[r][tx] = W[(size_t)(k0 + r) * N + n0 + tx];
  }
  __syncthreads();
#pragma unroll
  for (int i = 0; i < 16; ++i) {
    int r = ty + i * 4;
    WT[(size_t)(n0 + r) * K + k0 + tx] = f2bf(T[tx][r]);
  }
}

// ---------------- bf16 transpose of the V slice: Vtg[g][d][kv] -----------------
__global__ __launch_bounds__(256)
void transV_kernel(const short* __restrict__ Vsrc, short* __restrict__ Vtg) {
  __shared__ short T[64][72];
  const int tx = threadIdx.x, ty = threadIdx.y;   // (64,4)
  const int kv0 = blockIdx.x * 64, d0 = blockIdx.y * 64, g = blockIdx.z;
  const short* src = Vsrc + (size_t)kv0 * QKV_STRIDE + g * 128 + d0;
#pragma unroll
  for (int i = 0; i < 16; ++i) {
    int r = ty + i * 4;
    T[r][tx] = src[(size_t)r * QKV_STRIDE + tx];
  }
  __syncthreads();
  short* dst = Vtg + (size_t)g * 128 * 2048 + (size_t)d0 * 2048 + kv0;
#pragma unroll
  for (int i = 0; i < 16; ++i) {
    int r = ty + i * 4;
    dst[(size_t)r * 2048 + tx] = T[tx][r];
  }
}

// ---------------- fp32 -> bf16 elementwise (hidden states) ----------------
__global__ __launch_bounds__(256)
void conv16_kernel(const float* __restrict__ X, short* __restrict__ Y, int n4) {
  int i = blockIdx.x * 256 + threadIdx.x;
  if (i < n4) {
    fl4 v = *(const fl4*)&X[(size_t)i * 4];
    s16x4 o;
    o[0] = f2bf(v[0]); o[1] = f2bf(v[1]); o[2] = f2bf(v[2]); o[3] = f2bf(v[3]);
    *(s16x4*)&Y[(size_t)i * 4] = o;
  }
}

// ---------------- GEMM (r14 serial structure + XCD-swizzled 1D grid) -----------
// r18/r19/r20 ladder proved: at this tile, cross-block TLP (small LDS, many
// blocks/CU) beats every in-block pipeline variant. 32KB LDS, serial stage ->
// drain -> compute; bijective XCD swizzle keeps each XCD's A-panels in its L2.
template<int OUT_BF16>
__global__ __launch_bounds__(256)
void gemm_bb(const short* __restrict__ A, const short* __restrict__ Bt,
             void* __restrict__ Cv, int N, int K) {
  __shared__ short As[8192];   // 128 rows x 64 shorts, chunk-XOR swizzled (r&7)
  __shared__ short Bs[8192];
  const int tid = threadIdx.x;
  // XCD-swizzled block decode (gridDim.x % 8 == 0)
  const int per8 = gridDim.x >> 3;
  const int v = ((int)blockIdx.x & 7) * per8 + ((int)blockIdx.x >> 3);
  const int nbn = N >> 7;
  const int bm = v / nbn, bn = v % nbn;
  const int wid = tid >> 6, lane = tid & 63;
  const int wr = (wid >> 1) * 64, wc = (wid & 1) * 64;
  const int ar = lane & 15, g = lane >> 4;

  const f32x4 fz = {0.f, 0.f, 0.f, 0.f};
  f32x4 acc[4][4];
#pragma unroll
  for (int m = 0; m < 4; ++m)
#pragma unroll
    for (int n = 0; n < 4; ++n) acc[m][n] = fz;

  const short* Abase = A + (size_t)(bm * 128) * K;
  const short* Bbase = Bt + (size_t)(bn * 128) * K;
  const int u0 = wid * 256 + lane;

  for (int k0 = 0; k0 < K; k0 += 64) {
#pragma unroll
    for (int i = 0; i < 4; ++i) {
      int u = u0 + i * 64;
      int r = u >> 3;
      int cs = (u & 7) ^ (r & 7);
      size_t goff = (size_t)r * K + k0 + cs * 8;
      GLOAD_LDS16(Abase + goff, &As[u * 8]);
      GLOAD_LDS16(Bbase + goff, &Bs[u * 8]);
    }
    __syncthreads();
#pragma unroll
    for (int ks = 0; ks < 2; ++ks) {
      s16x8 af[4], bfr[4];
#pragma unroll
      for (int m = 0; m < 4; ++m) {
        int r = wr + m * 16 + ar;
        af[m] = *(const s16x8*)&As[r * 64 + (((ks * 4 + g) ^ (r & 7)) * 8)];
      }
#pragma unroll
      for (int n = 0; n < 4; ++n) {
        int r = wc + n * 16 + ar;
        bfr[n] = *(const s16x8*)&Bs[r * 64 + (((ks * 4 + g) ^ (r & 7)) * 8)];
      }
      __builtin_amdgcn_s_setprio(1);
#pragma unroll
      for (int m = 0; m < 4; ++m)
#pragma unroll
        for (int n = 0; n < 4; ++n)
          acc[m][n] = __builtin_amdgcn_mfma_f32_16x16x32_bf16(af[m], bfr[n], acc[m][n], 0, 0, 0);
      __builtin_amdgcn_s_setprio(0);
    }
    __syncthreads();
  }
  const int rr = (lane >> 4) * 4;
#pragma unroll
  for (int m = 0; m < 4; ++m)
#pragma unroll
    for (int n = 0; n < 4; ++n)
#pragma unroll
      for (int j = 0; j < 4; ++j) {
        int row = bm * 128 + wr + m * 16 + rr + j;
        int col = bn * 128 + wc + n * 16 + ar;
        if (OUT_BF16)
          ((short*)Cv)[(size_t)row * N + col] = f2bf(acc[m][n][j]);
        else
          ((float*)Cv)[(size_t)row * N + col] = acc[m][n][j];
      }
}

// ------- fused RMSNorm + RoPE on a column-slice of the fused QKV matrix --------
__global__ __launch_bounds__(256)
void normrope_kernel(short* __restrict__ X, const float* __restrict__ cosb,
                     const float* __restrict__ sinb, const float* __restrict__ w,
                     int hbits, int off, float scale) {
  const int wid = threadIdx.x >> 6, lane = threadIdx.x & 63;
  const int r = blockIdx.x * 4 + wid;
  const int s = r >> hbits, h = r & ((1 << hbits) - 1);
  const size_t base = (size_t)s * QKV_STRIDE + off + h * 128;
  float x1 = bf2f(X[base + lane]);
  float x2 = bf2f(X[base + 64 + lane]);
  float ss = x1 * x1 + x2 * x2;
#pragma unroll
  for (int m = 1; m < 64; m <<= 1) ss += __shfl_xor(ss, m);
  float inv = rsqrtf(ss * (1.0f / 128.0f) + 1e-6f) * scale;
  float n1 = x1 * inv * (1.0f + w[lane]);
  float n2 = x2 * inv * (1.0f + w[lane + 64]);
  float c1 = cosb[s * 128 + lane], sn1 = sinb[s * 128 + lane];
  float c2 = cosb[s * 128 + 64 + lane], sn2 = sinb[s * 128 + 64 + lane];
  X[base + lane] = f2bf(n1 * c1 - n2 * sn1);
  X[base + 64 + lane] = f2bf(n2 * c2 + n1 * sn2);
}

// ------------- flash attention v10: KVBLK=32 parity split, 64KB, 2 blocks/CU ---
// r20 lesson applied to attn: r14's 128KB LDS capped it at 1 block/CU (occ 19.9%
// vs 25% cap). KVBLK=32 halves LDS to 64KB -> 2 blocks/CU (16 waves). Same math
// per kv (16 MFMA + 16-score softcap per step, 2x steps). K swizzle unchanged
// (16 chunks/row); Vt rows are 4 chunks -> swizzle ^((d>>1)&3) (4-way PV read,
// 1.58x, acceptable). Parity partials combined via the single 64KB SMEM array
// in two phases (O then l).
__global__ __launch_bounds__(512, 4)
void attn_kernel(const short* __restrict__ C, const short* __restrict__ Vtg,
                 short* __restrict__ O) {
  __shared__ short SMEM[32768];   // 64KB: Ks = [0,16384), Vt = [16384,32768)
  const int tid = threadIdx.x;
  const int par = tid >> 8;                   // kv parity
  const int t256 = tid & 255;
  const int bid = blockIdx.x;
  const int g = bid & 7;                      // kv-head, pinned to XCD g
  const int i0 = bid >> 3;
  const int h = g * 4 + (i0 & 3);
  const int c = 15 - (i0 >> 2);               // LPT: big chunks dispatch first
  const int wid4 = (tid >> 6) & 3;            // wave-in-parity: q sub-chunk
  const int lane = tid & 63;
  const int q32 = lane & 31, hi = lane >> 5;
  const int qw0 = c * 128 + wid4 * 32;        // wave's 32 q-rows
  const int NS = 2 * c + 2;                   // 32-kv steps per parity (4c+4 total)

  const short* Kb = C + 4096 + g * 128;
  const short* Vb = Vtg + (size_t)g * 128 * 2048;

  // LDS sub-buffers: Ks[par][b] = 4096 shorts (32 kv x 128 d), Vt[par][b] same
  auto KsBase = [&](int p, int b) { return &SMEM[(p * 2 + b) * 4096]; };
  auto VtBase = [&](int p, int b) { return &SMEM[16384 + (p * 2 + b) * 4096]; };

  s16x8 qf[8];
  f32x16 oacc[4];
  float l_part = 0.f;

  const short* Qrow = C + (size_t)(qw0 + q32) * QKV_STRIDE + h * 128 + hi * 8;
#pragma unroll
  for (int t = 0; t < 8; ++t) qf[t] = *(const s16x8*)(Qrow + t * 16);
#pragma unroll
  for (int db = 0; db < 4; ++db)
#pragma unroll
    for (int r = 0; r < 16; ++r) oacc[db][r] = 0.f;

  auto issueK = [&](int b, int kb32) {
    short* dst = KsBase(par, b);
#pragma unroll
    for (int ii = 0; ii < 2; ++ii) {          // 2*256*16B = full 8KB tile
      int u = t256 + ii * 256;                // 512 chunks
      int r = u >> 4, cc = u & 15;            // r = kv row 0..31
      GLOAD_LDS16(Kb + (size_t)(kb32 * 32 + r) * QKV_STRIDE + ((cc ^ (r & 7)) * 8),
                  dst + u * 8);
    }
  };
  auto issueV = [&](int b, int kb32) {
    short* dst = VtBase(par, b);
#pragma unroll
    for (int ii = 0; ii < 2; ++ii) {
      int u = t256 + ii * 256;
      int d = u >> 2, cc = u & 3;             // d row 0..127, 4 chunks
      GLOAD_LDS16(Vb + (size_t)d * 2048 + kb32 * 32 + ((cc ^ ((d >> 1) & 3)) * 8),
                  dst + u * 8);
    }
  };

  // prologue: parity's first tile is tile `par`
  issueK(0, par);
  issueV(0, par);
  asm volatile("s_waitcnt vmcnt(0)" ::: "memory");
  __syncthreads();

  int buf = 0;
  for (int step = 0; step < NS; ++step) {
    const int kb32 = 2 * step + par;
    if (step + 1 < NS) { issueK(buf ^ 1, kb32 + 2); issueV(buf ^ 1, kb32 + 2); }

    if (!(kb32 * 32 > qw0 + 31)) {             // wave not fully masked
      // ---- S^T = K Q^T (Q pre-scaled): sacc[r] = y[kv=crow][q=q32] ----
      const short* ks = KsBase(par, buf);
      f32x16 sacc;
#pragma unroll
      for (int r = 0; r < 16; ++r) sacc[r] = 0.f;
      __builtin_amdgcn_s_setprio(1);
#pragma unroll
      for (int t = 0; t < 8; ++t) {
        s16x8 kf = *(const s16x8*)&ks[q32 * 128 + (((2 * t + hi) ^ (q32 & 7)) * 8)];
        sacc = __builtin_amdgcn_mfma_f32_32x32x16_bf16(kf, qf[t], sacc, 0, 0, 0);
      }
      __builtin_amdgcn_s_setprio(0);

      // ---- softcapped exp via exp2 (fixed max 0), causal mask ----
      const bool anymask = (kb32 * 32 + 31 > qw0);
#pragma unroll
      for (int r = 0; r < 16; ++r) {
        float y = sacc[r];
        float y2 = y * y;
        float z = y * fmaf(y2, fmaf(y2, PC2, PC1), L2E);
        float p = exp2f(z);
        if (anymask) {
          int kk = kb32 * 32 + (r & 3) + 8 * (r >> 2) + 4 * hi;
          if (kk > qw0 + q32) p = 0.f;
        }
        l_part += p;
        sacc[r] = p;
      }

      // ---- P -> A-frags: cvt_pk + permlane32_swap ; O += P V ----
      const short* vt = VtBase(par, buf);
#pragma unroll
      for (int ks2 = 0; ks2 < 2; ++ks2) {
        const int r0 = ks2 * 8;
        unsigned a0 = cvtpk(sacc[r0 + 0], sacc[r0 + 1]);
        unsigned a1 = cvtpk(sacc[r0 + 2], sacc[r0 + 3]);
        unsigned b0 = cvtpk(sacc[r0 + 4], sacc[r0 + 5]);
        unsigned b1 = cvtpk(sacc[r0 + 6], sacc[r0 + 7]);
        asm("v_permlane32_swap_b32 %0, %1" : "+v"(a0), "+v"(b0));
        asm("v_permlane32_swap_b32 %0, %1" : "+v"(a1), "+v"(b1));
        union { s16x8 v; unsigned w[4]; } pw;
        pw.w[0] = a0; pw.w[1] = a1; pw.w[2] = b0; pw.w[3] = b1;
        __builtin_amdgcn_s_setprio(1);
#pragma unroll
        for (int db = 0; db < 4; ++db) {
          int d = db * 32 + q32;
          s16x8 vf = *(const s16x8*)&vt[d * 32 + (((ks2 * 2 + hi) ^ ((d >> 1) & 3)) * 8)];
          oacc[db] = __builtin_amdgcn_mfma_f32_32x32x16_bf16(pw.v, vf, oacc[db], 0, 0, 0);
        }
        __builtin_amdgcn_s_setprio(0);
      }
    }

    // single sync point per step
    asm volatile("s_waitcnt vmcnt(0)" ::: "memory");
    __syncthreads();
    buf ^= 1;
  }

  // ---- combine parity partials (fixed-max => exactly additive), two phases ----
  float* sk = (float*)SMEM;                    // 16384 f32 = full 64KB
  const int lid = wid4 * 64 + lane;            // 0..255 within parity
  if (par == 1) {
#pragma unroll
    for (int db = 0; db < 4; ++db)
#pragma unroll
      for (int r = 0; r < 16; ++r) sk[lid + (db * 16 + r) * 256] = oacc[db][r];
  }
  __syncthreads();
  if (par == 0) {
#pragma unroll
    for (int db = 0; db < 4; ++db)
#pragma unroll
      for (int r = 0; r < 16; ++r) oacc[db][r] += sk[lid + (db * 16 + r) * 256];
  }
  __syncthreads();
  if (par == 1) sk[lid] = l_part;
  __syncthreads();
  if (par == 0) {
    l_part += sk[lid];
    // ---- epilogue: l gather, divide, store ----
    float lt = l_part + __shfl_xor(l_part, 32);
    float rl[16];
#pragma unroll
    for (int r = 0; r < 16; ++r)
      rl[r] = 1.0f / __shfl(lt, (r & 3) + 8 * (r >> 2) + 4 * hi);
#pragma unroll
    for (int db = 0; db < 4; ++db)
#pragma unroll
      for (int r = 0; r < 16; ++r) {
        int q = qw0 + (r & 3) + 8 * (r >> 2) + 4 * hi;
        int d = db * 32 + q32;
        O[(size_t)q * 4096 + h * 128 + d] = f2bf(oacc[db][r] * rl[r]);
      }
  }
}

extern "C" void kernel_launch(void* const* d_in, const int* in_sizes, int n_in,
                              void* d_out, int out_size, void* d_ws, size_t ws_size,
                              hipStream_t stream) {
  const float* hs   = (const float*)d_in[0];
  const float* cosb = (const float*)d_in[1];
  const float* sinb = (const float*)d_in[2];
  // d_in[3]: causal mask, applied analytically
  const float* Wq = (const float*)d_in[4];
  const float* Wk = (const float*)d_in[5];
  const float* Wv = (const float*)d_in[6];
  const float* Wo = (const float*)d_in[7];
  const float* qw = (const float*)d_in[8];
  const float* kw = (const float*)d_in[9];
  float* out = (float*)d_out;

  char* ws = (char*)d_ws;
  short* hsb = (short*)ws;                        // [0, 10.49M)  2048x2560
  short* WT  = (short*)(ws + 10485760);           // [10.49, 41.94M) 6144x2560 fused
  short* WkT = WT + (size_t)4096 * 2560;
  short* WvT = WT + (size_t)5120 * 2560;
  short* Cq  = (short*)(ws + 41943040);           // [41.94, 67.11M) 2048x6144 QKV
  short* ao  = (short*)ws;                        // [0, 16.78M) alias (dead after GEMMs)
  short* Vtg = (short*)(ws + 16777216);           // [16.78, 20.97M) 8x128x2048 (4MB gap)
  short* WoT = (short*)(ws + 20971520);           // [20.97, 41.94M) alias WT-tail

  dim3 blk(256), cblk(64, 4);
  convT_kernel<<<dim3(40, 64), cblk, 0, stream>>>(Wq, WT, 2560, 4096);
  convT_kernel<<<dim3(40, 16), cblk, 0, stream>>>(Wk, WkT, 2560, 1024);
  convT_kernel<<<dim3(40, 16), cblk, 0, stream>>>(Wv, WvT, 2560, 1024);
  conv16_kernel<<<5120, blk, 0, stream>>>(hs, hsb, 1310720);
  gemm_bb<1><<<dim3(768), blk, 0, stream>>>(hsb, WT, Cq, 6144, 2560);
  normrope_kernel<<<16384, blk, 0, stream>>>(Cq, cosb, sinb, qw, 5, 0, SCALING_C);
  normrope_kernel<<<4096,  blk, 0, stream>>>(Cq, cosb, sinb, kw, 3, 4096, 1.0f);
  transV_kernel<<<dim3(32, 2, 8), cblk, 0, stream>>>(Cq + 5120, Vtg);
  convT_kernel<<<dim3(64, 40), cblk, 0, stream>>>(Wo, WoT, 4096, 2560);
  attn_kernel<<<dim3(512), dim3(512), 0, stream>>>(Cq, Vtg, ao);
  gemm_bb<0><<<dim3(320), blk, 0, stream>>>(ao, WoT, out, 2560, 4096);
}

// Round 22
// 266.656 us; speedup vs baseline: 1.4557x; 1.2126x over previous
//
#include <hip/hip_runtime.h>
#include <hip/hip_bf16.h>

typedef __attribute__((ext_vector_type(4))) float f32x4;
typedef __attribute__((ext_vector_type(16))) float f32x16;
typedef __attribute__((ext_vector_type(4))) float fl4;
typedef __attribute__((ext_vector_type(8))) short s16x8;
typedef __attribute__((ext_vector_type(4))) short s16x4;

#define SCALING_C 0.1889822365046136f
// p = exp(50*tanh(y/50)) = exp2(y*(L + y2*(P1*L + y2*P2*L))), L=log2(e)
#define L2E 1.4426950408889634f
#define PC1 (-1.9235933e-4f)   // -1/7500 * L2E
#define PC2 (3.0777493e-8f)    //  2/93750000 * L2E
#define QKV_STRIDE 6144

__device__ __forceinline__ short f2bf(float f) {
  union { float f; unsigned u; } v; v.f = f;
  unsigned r = v.u + 0x7fffu + ((v.u >> 16) & 1u);
  return (short)(r >> 16);
}
__device__ __forceinline__ float bf2f(short s) {
  union { unsigned u; float f; } v; v.u = ((unsigned)(unsigned short)s) << 16;
  return v.f;
}
__device__ __forceinline__ unsigned cvtpk(float a, float b) {
  unsigned r;
  asm("v_cvt_pk_bf16_f32 %0, %1, %2" : "=v"(r) : "v"(a), "v"(b));
  return r;   // D[15:0]=bf16(a), D[31:16]=bf16(b)
}

#define GLOAD_LDS16(g, l)                                                          \
  __builtin_amdgcn_global_load_lds(                                                \
      (const __attribute__((address_space(1))) void*)(g),                          \
      (__attribute__((address_space(3))) void*)(l), 16, 0, 0)

// ---------------- transpose + fp32->bf16 convert: WT[n][k] = bf16(W[k][n]) -----
__global__ __launch_bounds__(256)
void convT_kernel(const float* __restrict__ W, short* __restrict__ WT, int K, int N) {
  __shared__ float T[64][65];
  const int tx = threadIdx.x, ty = threadIdx.y;   // (64,4)
  const int k0 = blockIdx.x * 64, n0 = blockIdx.y * 64;
#pragma unroll
  for (int i = 0; i < 16; ++i) {
    int r = ty + i * 4;
    T[r][tx] = W[(size_t)(k0 + r) * N + n0 + tx];
  }
  __syncthreads();
#pragma unroll
  for (int i = 0; i < 16; ++i) {
    int r = ty + i * 4;
    WT[(size_t)(n0 + r) * K + k0 + tx] = f2bf(T[tx][r]);
  }
}

// ---------------- bf16 transpose of the V slice: Vtg[g][d][kv] -----------------
__global__ __launch_bounds__(256)
void transV_kernel(const short* __restrict__ Vsrc, short* __restrict__ Vtg) {
  __shared__ short T[64][72];
  const int tx = threadIdx.x, ty = threadIdx.y;   // (64,4)
  const int kv0 = blockIdx.x * 64, d0 = blockIdx.y * 64, g = blockIdx.z;
  const short* src = Vsrc + (size_t)kv0 * QKV_STRIDE + g * 128 + d0;
#pragma unroll
  for (int i = 0; i < 16; ++i) {
    int r = ty + i * 4;
    T[r][tx] = src[(size_t)r * QKV_STRIDE + tx];
  }
  __syncthreads();
  short* dst = Vtg + (size_t)g * 128 * 2048 + (size_t)d0 * 2048 + kv0;
#pragma unroll
  for (int i = 0; i < 16; ++i) {
    int r = ty + i * 4;
    dst[(size_t)r * 2048 + tx] = T[tx][r];
  }
}

// ---------------- fp32 -> bf16 elementwise (hidden states) ----------------
__global__ __launch_bounds__(256)
void conv16_kernel(const float* __restrict__ X, short* __restrict__ Y, int n4) {
  int i = blockIdx.x * 256 + threadIdx.x;
  if (i < n4) {
    fl4 v = *(const fl4*)&X[(size_t)i * 4];
    s16x4 o;
    o[0] = f2bf(v[0]); o[1] = f2bf(v[1]); o[2] = f2bf(v[2]); o[3] = f2bf(v[3]);
    *(s16x4*)&Y[(size_t)i * 4] = o;
  }
}

// ---------------- GEMM (r14 serial structure + XCD-swizzled 1D grid) -----------
// r18/r19/r20 ladder: at this tile, cross-block TLP (32KB LDS, ~4-5 blocks/CU)
// beats every in-block pipeline variant. Serial stage -> drain -> compute.
template<int OUT_BF16>
__global__ __launch_bounds__(256)
void gemm_bb(const short* __restrict__ A, const short* __restrict__ Bt,
             void* __restrict__ Cv, int N, int K) {
  __shared__ short As[8192];   // 128 rows x 64 shorts, chunk-XOR swizzled (r&7)
  __shared__ short Bs[8192];
  const int tid = threadIdx.x;
  // XCD-swizzled block decode (gridDim.x % 8 == 0)
  const int per8 = gridDim.x >> 3;
  const int v = ((int)blockIdx.x & 7) * per8 + ((int)blockIdx.x >> 3);
  const int nbn = N >> 7;
  const int bm = v / nbn, bn = v % nbn;
  const int wid = tid >> 6, lane = tid & 63;
  const int wr = (wid >> 1) * 64, wc = (wid & 1) * 64;
  const int ar = lane & 15, g = lane >> 4;

  const f32x4 fz = {0.f, 0.f, 0.f, 0.f};
  f32x4 acc[4][4];
#pragma unroll
  for (int m = 0; m < 4; ++m)
#pragma unroll
    for (int n = 0; n < 4; ++n) acc[m][n] = fz;

  const short* Abase = A + (size_t)(bm * 128) * K;
  const short* Bbase = Bt + (size_t)(bn * 128) * K;
  const int u0 = wid * 256 + lane;

  for (int k0 = 0; k0 < K; k0 += 64) {
#pragma unroll
    for (int i = 0; i < 4; ++i) {
      int u = u0 + i * 64;
      int r = u >> 3;
      int cs = (u & 7) ^ (r & 7);
      size_t goff = (size_t)r * K + k0 + cs * 8;
      GLOAD_LDS16(Abase + goff, &As[u * 8]);
      GLOAD_LDS16(Bbase + goff, &Bs[u * 8]);
    }
    __syncthreads();
#pragma unroll
    for (int ks = 0; ks < 2; ++ks) {
      s16x8 af[4], bfr[4];
#pragma unroll
      for (int m = 0; m < 4; ++m) {
        int r = wr + m * 16 + ar;
        af[m] = *(const s16x8*)&As[r * 64 + (((ks * 4 + g) ^ (r & 7)) * 8)];
      }
#pragma unroll
      for (int n = 0; n < 4; ++n) {
        int r = wc + n * 16 + ar;
        bfr[n] = *(const s16x8*)&Bs[r * 64 + (((ks * 4 + g) ^ (r & 7)) * 8)];
      }
      __builtin_amdgcn_s_setprio(1);
#pragma unroll
      for (int m = 0; m < 4; ++m)
#pragma unroll
        for (int n = 0; n < 4; ++n)
          acc[m][n] = __builtin_amdgcn_mfma_f32_16x16x32_bf16(af[m], bfr[n], acc[m][n], 0, 0, 0);
      __builtin_amdgcn_s_setprio(0);
    }
    __syncthreads();
  }
  const int rr = (lane >> 4) * 4;
#pragma unroll
  for (int m = 0; m < 4; ++m)
#pragma unroll
    for (int n = 0; n < 4; ++n)
#pragma unroll
      for (int j = 0; j < 4; ++j) {
        int row = bm * 128 + wr + m * 16 + rr + j;
        int col = bn * 128 + wc + n * 16 + ar;
        if (OUT_BF16)
          ((short*)Cv)[(size_t)row * N + col] = f2bf(acc[m][n][j]);
        else
          ((float*)Cv)[(size_t)row * N + col] = acc[m][n][j];
      }
}

// ------- fused RMSNorm + RoPE on a column-slice of the fused QKV matrix --------
// scale folds the attention SCALING into Q (1.0 for K).
__global__ __launch_bounds__(256)
void normrope_kernel(short* __restrict__ X, const float* __restrict__ cosb,
                     const float* __restrict__ sinb, const float* __restrict__ w,
                     int hbits, int off, float scale) {
  const int wid = threadIdx.x >> 6, lane = threadIdx.x & 63;
  const int r = blockIdx.x * 4 + wid;
  const int s = r >> hbits, h = r & ((1 << hbits) - 1);
  const size_t base = (size_t)s * QKV_STRIDE + off + h * 128;
  float x1 = bf2f(X[base + lane]);
  float x2 = bf2f(X[base + 64 + lane]);
  float ss = x1 * x1 + x2 * x2;
#pragma unroll
  for (int m = 1; m < 64; m <<= 1) ss += __shfl_xor(ss, m);
  float inv = rsqrtf(ss * (1.0f / 128.0f) + 1e-6f) * scale;
  float n1 = x1 * inv * (1.0f + w[lane]);
  float n2 = x2 * inv * (1.0f + w[lane + 64]);
  float c1 = cosb[s * 128 + lane], sn1 = sinb[s * 128 + lane];
  float c2 = cosb[s * 128 + 64 + lane], sn2 = sinb[s * 128 + 64 + lane];
  X[base + lane] = f2bf(n1 * c1 - n2 * sn1);
  X[base + 64 + lane] = f2bf(n2 * c2 + n1 * sn2);
}

// ------------- flash attention v9 (r14 verbatim): kv-parity, KVBLK=64 ----------
// Best measured attn (92.2us). 512 thr: waves 0-3 even kv-tiles, 4-7 odd, each
// parity a dbuf gload_lds stream (128KB, 1 block/CU); XCD-pinned; fixed-max
// softmax (softcap bounds s); cvt_pk+permlane32_swap P repack; poly-in-exp2.
__global__ __launch_bounds__(512, 2)
void attn_kernel(const short* __restrict__ C, const short* __restrict__ Vtg,
                 short* __restrict__ O) {
  __shared__ short Ks[2][2][8192];   // [par][buf][kv 64][d 128], chunk-XOR (r&7)
  __shared__ short Vt[2][2][8192];   // [par][buf][d 128][kv 64], chunk-XOR (d&7)
  const int tid = threadIdx.x;
  const int par = tid >> 8;                   // kv parity
  const int t256 = tid & 255;
  const int bid = blockIdx.x;
  const int g = bid & 7;                      // kv-head, pinned to XCD g
  const int i0 = bid >> 3;
  const int h = g * 4 + (i0 & 3);
  const int c = 15 - (i0 >> 2);               // LPT: big chunks dispatch first
  const int wid4 = (tid >> 6) & 3;            // wave-in-parity: q sub-chunk
  const int lane = tid & 63;
  const int q32 = lane & 31, hi = lane >> 5;
  const int qw0 = c * 128 + wid4 * 32;        // wave's 32 q-rows
  const int NS = c + 1;                       // steps per parity (NT = 2c+2)

  const short* Kb = C + 4096 + g * 128;
  const short* Vb = Vtg + (size_t)g * 128 * 2048;

  s16x8 qf[8];
  f32x16 oacc[4];
  float l_part = 0.f;

  const short* Qrow = C + (size_t)(qw0 + q32) * QKV_STRIDE + h * 128 + hi * 8;
#pragma unroll
  for (int t = 0; t < 8; ++t) qf[t] = *(const s16x8*)(Qrow + t * 16);
#pragma unroll
  for (int db = 0; db < 4; ++db)
#pragma unroll
    for (int r = 0; r < 16; ++r) oacc[db][r] = 0.f;

  auto issueK = [&](int b, int kb) {
#pragma unroll
    for (int ii = 0; ii < 4; ++ii) {          // 4*256*16B = full 16KB tile
      int u = t256 + ii * 256;
      int r = u >> 4, cc = u & 15;
      GLOAD_LDS16(Kb + (size_t)(kb * 64 + r) * QKV_STRIDE + ((cc ^ (r & 7)) * 8),
                  &Ks[par][b][u * 8]);
    }
  };
  auto issueV = [&](int b, int kb) {
#pragma unroll
    for (int ii = 0; ii < 4; ++ii) {
      int u = t256 + ii * 256;
      int d = u >> 3, cc = u & 7;
      GLOAD_LDS16(Vb + (size_t)d * 2048 + kb * 64 + ((cc ^ (d & 7)) * 8),
                  &Vt[par][b][u * 8]);
    }
  };

  // prologue: parity's first tile is tile `par`
  issueK(0, par);
  issueV(0, par);
  asm volatile("s_waitcnt vmcnt(0)" ::: "memory");
  __syncthreads();

  int buf = 0;
  for (int step = 0; step < NS; ++step) {
    const int kb = 2 * step + par;
    if (step + 1 < NS) { issueK(buf ^ 1, kb + 2); issueV(buf ^ 1, kb + 2); }

    if (!(kb * 64 > qw0 + 31)) {               // wave not fully masked
      // ---- S^T = K Q^T (Q pre-scaled): sacc[m][r] = y[k=crow][q=q32] ----
      f32x16 sacc[2];
#pragma unroll
      for (int m = 0; m < 2; ++m)
#pragma unroll
        for (int r = 0; r < 16; ++r) sacc[m][r] = 0.f;
      __builtin_amdgcn_s_setprio(1);
#pragma unroll
      for (int t = 0; t < 8; ++t)
#pragma unroll
        for (int m = 0; m < 2; ++m) {
          int r = m * 32 + q32;
          s16x8 kf = *(const s16x8*)&Ks[par][buf][r * 128 + (((2 * t + hi) ^ (r & 7)) * 8)];
          sacc[m] = __builtin_amdgcn_mfma_f32_32x32x16_bf16(kf, qf[t], sacc[m], 0, 0, 0);
        }
      __builtin_amdgcn_s_setprio(0);

      // ---- softcapped exp via exp2 (fixed max 0), causal mask ----
      const bool anymask = (kb * 64 + 63 > qw0);
#pragma unroll
      for (int m = 0; m < 2; ++m)
#pragma unroll
        for (int r = 0; r < 16; ++r) {
          float y = sacc[m][r];
          float y2 = y * y;
          float z = y * fmaf(y2, fmaf(y2, PC2, PC1), L2E);
          float p = exp2f(z);
          if (anymask) {
            int kk = kb * 64 + m * 32 + (r & 3) + 8 * (r >> 2) + 4 * hi;
            if (kk > qw0 + q32) p = 0.f;
          }
          l_part += p;
          sacc[m][r] = p;
        }

      // ---- P -> A-frags: cvt_pk + permlane32_swap ; O += P V ----
#pragma unroll
      for (int ks = 0; ks < 4; ++ks) {
        const int m = ks >> 1, r0 = (ks & 1) * 8;
        unsigned a0 = cvtpk(sacc[m][r0 + 0], sacc[m][r0 + 1]);
        unsigned a1 = cvtpk(sacc[m][r0 + 2], sacc[m][r0 + 3]);
        unsigned b0 = cvtpk(sacc[m][r0 + 4], sacc[m][r0 + 5]);
        unsigned b1 = cvtpk(sacc[m][r0 + 6], sacc[m][r0 + 7]);
        // swap: a' = lane<32 ? a : b[lane-32]; b' = lane<32 ? a[lane+32] : b
        asm("v_permlane32_swap_b32 %0, %1" : "+v"(a0), "+v"(b0));
        asm("v_permlane32_swap_b32 %0, %1" : "+v"(a1), "+v"(b1));
        union { s16x8 v; unsigned w[4]; } pw;
        pw.w[0] = a0; pw.w[1] = a1; pw.w[2] = b0; pw.w[3] = b1;
        __builtin_amdgcn_s_setprio(1);
#pragma unroll
        for (int db = 0; db < 4; ++db) {
          int d = db * 32 + q32;
          s16x8 vf = *(const s16x8*)&Vt[par][buf][d * 64 + (((2 * ks + hi) ^ (d & 7)) * 8)];
          oacc[db] = __builtin_amdgcn_mfma_f32_32x32x16_bf16(pw.v, vf, oacc[db], 0, 0, 0);
        }
        __builtin_amdgcn_s_setprio(0);
      }
    }

    // single sync point per step
    asm volatile("s_waitcnt vmcnt(0)" ::: "memory");
    __syncthreads();
    buf ^= 1;
  }

  // ---- combine parity partials (fixed-max => exactly additive) ----
  float* sk = (float*)&Ks[0][0][0];            // 64KB: 256 lanes x 64 f32
  float* lv = (float*)&Vt[0][0][0];            // 1KB: 256 lanes
  const int lid = wid4 * 64 + lane;
  if (par == 1) {
#pragma unroll
    for (int db = 0; db < 4; ++db)
#pragma unroll
      for (int r = 0; r < 16; ++r) sk[lid + (db * 16 + r) * 256] = oacc[db][r];
    lv[lid] = l_part;
  }
  __syncthreads();
  if (par == 0) {
#pragma unroll
    for (int db = 0; db < 4; ++db)
#pragma unroll
      for (int r = 0; r < 16; ++r) oacc[db][r] += sk[lid + (db * 16 + r) * 256];
    l_part += lv[lid];

    // ---- epilogue: l gather, divide, store ----
    float lt = l_part + __shfl_xor(l_part, 32);
    float rl[16];
#pragma unroll
    for (int r = 0; r < 16; ++r)
      rl[r] = 1.0f / __shfl(lt, (r & 3) + 8 * (r >> 2) + 4 * hi);
#pragma unroll
    for (int db = 0; db < 4; ++db)
#pragma unroll
      for (int r = 0; r < 16; ++r) {
        int q = qw0 + (r & 3) + 8 * (r >> 2) + 4 * hi;
        int d = db * 32 + q32;
        O[(size_t)q * 4096 + h * 128 + d] = f2bf(oacc[db][r] * rl[r]);
      }
  }
}

extern "C" void kernel_launch(void* const* d_in, const int* in_sizes, int n_in,
                              void* d_out, int out_size, void* d_ws, size_t ws_size,
                              hipStream_t stream) {
  const float* hs   = (const float*)d_in[0];
  const float* cosb = (const float*)d_in[1];
  const float* sinb = (const float*)d_in[2];
  // d_in[3]: causal mask, applied analytically
  const float* Wq = (const float*)d_in[4];
  const float* Wk = (const float*)d_in[5];
  const float* Wv = (const float*)d_in[6];
  const float* Wo = (const float*)d_in[7];
  const float* qw = (const float*)d_in[8];
  const float* kw = (const float*)d_in[9];
  float* out = (float*)d_out;

  char* ws = (char*)d_ws;
  short* hsb = (short*)ws;                        // [0, 10.49M)  2048x2560
  short* WT  = (short*)(ws + 10485760);           // [10.49, 41.94M) 6144x2560 fused
  short* WkT = WT + (size_t)4096 * 2560;
  short* WvT = WT + (size_t)5120 * 2560;
  short* Cq  = (short*)(ws + 41943040);           // [41.94, 67.11M) 2048x6144 QKV
  short* ao  = (short*)ws;                        // [0, 16.78M) alias (dead after GEMMs)
  short* Vtg = (short*)(ws + 16777216);           // [16.78, 20.97M) 8x128x2048 (4MB gap)
  short* WoT = (short*)(ws + 20971520);           // [20.97, 41.94M) alias WT-tail

  dim3 blk(256), cblk(64, 4);
  convT_kernel<<<dim3(40, 64), cblk, 0, stream>>>(Wq, WT, 2560, 4096);
  convT_kernel<<<dim3(40, 16), cblk, 0, stream>>>(Wk, WkT, 2560, 1024);
  convT_kernel<<<dim3(40, 16), cblk, 0, stream>>>(Wv, WvT, 2560, 1024);
  conv16_kernel<<<5120, blk, 0, stream>>>(hs, hsb, 1310720);
  gemm_bb<1><<<dim3(768), blk, 0, stream>>>(hsb, WT, Cq, 6144, 2560);
  normrope_kernel<<<16384, blk, 0, stream>>>(Cq, cosb, sinb, qw, 5, 0, SCALING_C);
  normrope_kernel<<<4096,  blk, 0, stream>>>(Cq, cosb, sinb, kw, 3, 4096, 1.0f);
  transV_kernel<<<dim3(32, 2, 8), cblk, 0, stream>>>(Cq + 5120, Vtg);
  convT_kernel<<<dim3(64, 40), cblk, 0, stream>>>(Wo, WoT, 4096, 2560);
  attn_kernel<<<dim3(512), dim3(512), 0, stream>>>(Cq, Vtg, ao);
  gemm_bb<0><<<dim3(320), blk, 0, stream>>>(ao, WoT, out, 2560, 4096);
}